// Round 6
// baseline (450.563 us; speedup 1.0000x reference)
//
#include <hip/hip_runtime.h>
#include <hip/hip_bf16.h>

#define B_N 512
#define L_N 200
#define E_N 128
#define K_N 384
#define D_N 384
#define ASTR 392   // Alds row stride in bf16 elems: 3*128 + 8 pad (784 B, 16B-aligned)

typedef __bf16 v8bf  __attribute__((ext_vector_type(8)));
typedef float  v4f   __attribute__((ext_vector_type(4)));
typedef unsigned int v4u __attribute__((ext_vector_type(4)));

__device__ __forceinline__ unsigned short f2bf(float f) {
    union { __bf16 b; unsigned short u; } cv;
    cv.b = (__bf16)f;   // RNE
    return cv.u;
}
__device__ __forceinline__ float fast_tanh(float x) {
    float e = __expf(2.f * x);
    return 1.f - 2.f / (e + 1.f);
}

// Wp layout (PROVEN R2/R4/R5): frag (kk in [0,12), gn in [0,24)) at
// ((kk*24+gn)*64+lane)*8 bf16 = W[n=gn*16+(lane&15)][k=kk*32+(lane>>4)*8 ..+7]
__global__ void pack_w(const float* __restrict__ W, unsigned short* __restrict__ Wp) {
    int gid  = blockIdx.x * 256 + threadIdx.x;   // 18432
    int lane = gid & 63;
    int u    = gid >> 6;                         // [0,288)
    int gn   = u % 24;
    int kk   = u / 24;
    int c    = lane & 15, quad = lane >> 4;
    const float* src = W + (gn * 16 + c) * K_N + kk * 32 + quad * 8;
    ushort4 lo, hi;
    lo.x = f2bf(src[0]); lo.y = f2bf(src[1]); lo.z = f2bf(src[2]); lo.w = f2bf(src[3]);
    hi.x = f2bf(src[4]); hi.y = f2bf(src[5]); hi.z = f2bf(src[6]); hi.w = f2bf(src[7]);
    ushort4* dst = (ushort4*)(Wp + (size_t)gid * 8);
    dst[0] = lo; dst[1] = hi;
}

// One block per (b, pass); 512 threads = 8 waves; wave owns cols wv*48..+47.
// M in 4 IDENTICAL chunks of 64 rows (rows >= 200 zero-padded, weight 0 via
// -1e30 score). acc[4][3] v4f = 48 regs, all indexing compile-time constant.
__global__ __launch_bounds__(512, 4)
void c2v_fused(const int* __restrict__ xs1, const int* __restrict__ ph1,
               const int* __restrict__ xt1,
               const int* __restrict__ xs2, const int* __restrict__ ph2,
               const int* __restrict__ xt2,
               const float* __restrict__ wemb, const float* __restrict__ pemb,
               const unsigned short* __restrict__ Wp,
               const float* __restrict__ attn,
               float* __restrict__ out)
{
    const int tid  = threadIdx.x;
    const int wv   = tid >> 6;
    const int lane = tid & 63;
    const int quad = lane >> 4;
    const int c    = lane & 15;
    const int b    = blockIdx.x;
    const int pass = blockIdx.y;

    const int* xs = pass ? xs2 : xs1;
    const int* ph = pass ? ph2 : ph1;
    const int* xt = pass ? xt2 : xt1;

    __shared__ unsigned short Alds[64 * ASTR];   // 50176 B: one 64-row chunk, all 384 k
    __shared__ float sp[8][64];                  // per-wave score partials
    __shared__ float alds[68];                   // [0..63] e, [64] alpha, [65] Z
    __shared__ int   ilds[3 * 208];

    for (int u = tid; u < 624; u += 512) {
        int s = u / 208, g = u - s * 208;
        const int* tab = (s == 0) ? xs : (s == 1) ? ph : xt;
        ilds[u] = (g < L_N) ? tab[b * L_N + g] : 0;
    }

    const float an0 = attn[(wv * 3 + 0) * 16 + c];
    const float an1 = attn[(wv * 3 + 1) * 16 + c];
    const float an2 = attn[(wv * 3 + 2) * 16 + c];

    float o0 = 0.f, o1 = 0.f, o2 = 0.f;   // running unnormalized col sums
    float Mrun = -1e30f, Zrun = 0.f;      // wave-0 softmax state (uniform in wave)

    const v4u* wp4 = (const v4u*)Wp;

    for (int chunk = 0; chunk < 4; ++chunk) {
        const int row0 = chunk * 64;

        v4f acc[4][3];
        #pragma unroll
        for (int i = 0; i < 4; ++i)
            #pragma unroll
            for (int j = 0; j < 3; ++j)
                acc[i][j] = (v4f){0.f, 0.f, 0.f, 0.f};

        // hoist kk=0 Wp prefetch: L2 latency hides under the staging phase
        v4u nb0 = wp4[(0 * 24 + wv * 3 + 0) * 64 + lane];
        v4u nb1 = wp4[(0 * 24 + wv * 3 + 1) * 64 + lane];
        v4u nb2 = wp4[(0 * 24 + wv * 3 + 2) * 64 + lane];

        __syncthreads();   // Alds/sp/alds of previous chunk fully consumed

        // stage 64 rows x 3 segs x 128 elems = 24576 elems as 3072 8-elem units
        // (6/thread). Decode: s=seg, m=row-in-chunk, j=8-elem unit in seg.
        // 16 consecutive lanes cover one row's 512 B contiguously (coalesced);
        // each element loaded/converted/written exactly ONCE.
        #pragma unroll
        for (int i = 0; i < 6; ++i) {
            int u = i * 512 + tid;
            int s = u >> 10;            // seg 0..2 (1024 units per seg)
            int r = u & 1023;
            int m = r >> 4;             // row within chunk, 0..63
            int j = r & 15;             // 8-elem unit within seg, 0..15
            int g = row0 + m;
            ushort4 lo, hi;
            if (g < L_N) {
                const float* ebase = (s == 1) ? pemb : wemb;
                const float* src = ebase + (size_t)ilds[s * 208 + g] * E_N + j * 8;
                const float4 f0 = *(const float4*)(src);
                const float4 f1 = *(const float4*)(src + 4);
                lo.x = f2bf(f0.x); lo.y = f2bf(f0.y); lo.z = f2bf(f0.z); lo.w = f2bf(f0.w);
                hi.x = f2bf(f1.x); hi.y = f2bf(f1.y); hi.z = f2bf(f1.z); hi.w = f2bf(f1.w);
            } else {
                lo.x = lo.y = lo.z = lo.w = 0;
                hi.x = hi.y = hi.z = hi.w = 0;
            }
            ushort4* dst = (ushort4*)&Alds[m * ASTR + s * 128 + j * 8];
            dst[0] = lo; dst[1] = hi;
        }
        __syncthreads();

        // 12 k-steps, no barriers inside; Wp b-frags prefetched one kk ahead
        for (int kk = 0; kk < 12; ++kk) {
            v8bf b0 = __builtin_bit_cast(v8bf, nb0);
            v8bf b1 = __builtin_bit_cast(v8bf, nb1);
            v8bf b2 = __builtin_bit_cast(v8bf, nb2);
            if (kk < 11) {
                nb0 = wp4[((kk + 1) * 24 + wv * 3 + 0) * 64 + lane];
                nb1 = wp4[((kk + 1) * 24 + wv * 3 + 1) * 64 + lane];
                nb2 = wp4[((kk + 1) * 24 + wv * 3 + 2) * 64 + lane];
            }
            #pragma unroll
            for (int mt = 0; mt < 4; ++mt) {
                v8bf a = *(const v8bf*)&Alds[(mt * 16 + c) * ASTR + kk * 32 + quad * 8];
                acc[mt][0] = __builtin_amdgcn_mfma_f32_16x16x32_bf16(a, b0, acc[mt][0], 0, 0, 0);
                acc[mt][1] = __builtin_amdgcn_mfma_f32_16x16x32_bf16(a, b1, acc[mt][1], 0, 0, 0);
                acc[mt][2] = __builtin_amdgcn_mfma_f32_16x16x32_bf16(a, b2, acc[mt][2], 0, 0, 0);
            }
        }

        // tanh + per-wave score partials (all-constant indexing)
        #pragma unroll
        for (int mt = 0; mt < 4; ++mt) {
            #pragma unroll
            for (int r = 0; r < 4; ++r) {
                float h0 = fast_tanh(acc[mt][0][r]);
                float h1 = fast_tanh(acc[mt][1][r]);
                float h2 = fast_tanh(acc[mt][2][r]);
                acc[mt][0][r] = h0; acc[mt][1][r] = h1; acc[mt][2][r] = h2;
                float sv = h0 * an0 + h1 * an1 + h2 * an2;
                sv += __shfl_xor(sv, 1);
                sv += __shfl_xor(sv, 2);
                sv += __shfl_xor(sv, 4);
                sv += __shfl_xor(sv, 8);
                if (c == 0) sp[wv][mt * 16 + quad * 4 + r] = sv;
            }
        }
        __syncthreads();

        // wave 0: one lane per row; chunk softmax piece + online merge
        if (wv == 0) {
            int g = row0 + lane;
            float s = sp[0][lane] + sp[1][lane] + sp[2][lane] + sp[3][lane]
                    + sp[4][lane] + sp[5][lane] + sp[6][lane] + sp[7][lane];
            if (g >= L_N) s = -1e30f;
            float mx = s;
            #pragma unroll
            for (int off = 32; off > 0; off >>= 1) mx = fmaxf(mx, __shfl_xor(mx, off));
            float Mnew  = fmaxf(Mrun, mx);
            float alpha = __expf(Mrun - Mnew);
            float e = (g < L_N) ? __expf(s - Mnew) : 0.f;
            float zc = e;
            #pragma unroll
            for (int off = 32; off > 0; off >>= 1) zc += __shfl_xor(zc, off);
            Zrun = Zrun * alpha + zc;
            Mrun = Mnew;
            alds[lane] = e;
            if (lane == 0) alds[64] = alpha;
        }
        __syncthreads();

        // rescale running O, add this chunk's weighted rows
        const float al = alds[64];
        float p0 = 0.f, p1 = 0.f, p2 = 0.f;
        #pragma unroll
        for (int mt = 0; mt < 4; ++mt) {
            #pragma unroll
            for (int r = 0; r < 4; ++r) {
                float w = alds[mt * 16 + quad * 4 + r];
                p0 += w * acc[mt][0][r];
                p1 += w * acc[mt][1][r];
                p2 += w * acc[mt][2][r];
            }
        }
        o0 = o0 * al + p0;
        o1 = o1 * al + p1;
        o2 = o2 * al + p2;
    }

    if (tid == 0) alds[65] = Zrun;
    __syncthreads();
    const float zinv = 1.f / alds[65];

    float* outp = out + (size_t)(pass * B_N + b) * D_N;
    o0 += __shfl_xor(o0, 16); o0 += __shfl_xor(o0, 32);
    o1 += __shfl_xor(o1, 16); o1 += __shfl_xor(o1, 32);
    o2 += __shfl_xor(o2, 16); o2 += __shfl_xor(o2, 32);
    if (quad == 0) {
        outp[(wv * 3 + 0) * 16 + c] = o0 * zinv;
        outp[(wv * 3 + 1) * 16 + c] = o1 * zinv;
        outp[(wv * 3 + 2) * 16 + c] = o2 * zinv;
    }
}

extern "C" void kernel_launch(void* const* d_in, const int* in_sizes, int n_in,
                              void* d_out, int out_size, void* d_ws, size_t ws_size,
                              hipStream_t stream) {
    unsigned short* Wp = (unsigned short*)d_ws;   // 294912 B
    pack_w<<<72, 256, 0, stream>>>((const float*)d_in[8], Wp);
    dim3 grid(B_N, 2, 1);
    c2v_fused<<<grid, 512, 0, stream>>>(
        (const int*)d_in[0], (const int*)d_in[1], (const int*)d_in[2],
        (const int*)d_in[3], (const int*)d_in[4], (const int*)d_in[5],
        (const float*)d_in[6], (const float*)d_in[7],
        Wp, (const float*)d_in[9],
        (float*)d_out);
}

// Round 7
// 303.605 us; speedup vs baseline: 1.4840x; 1.4840x over previous
//
#include <hip/hip_runtime.h>
#include <hip/hip_bf16.h>

#define B_N 512
#define L_N 200
#define E_N 128
#define K_N 384
#define D_N 384
#define ASTR 392   // Alds row stride in bf16 elems: 3*128 + 8 pad (784 B, 16B-aligned)

typedef __bf16 v8bf  __attribute__((ext_vector_type(8)));
typedef float  v4f   __attribute__((ext_vector_type(4)));
typedef unsigned int v4u __attribute__((ext_vector_type(4)));

__device__ __forceinline__ unsigned short f2bf(float f) {
    union { __bf16 b; unsigned short u; } cv;
    cv.b = (__bf16)f;   // RNE
    return cv.u;
}
__device__ __forceinline__ float fast_tanh(float x) {
    float e = __expf(2.f * x);
    return 1.f - 2.f / (e + 1.f);
}

// Wp layout (PROVEN R2/R4/R5): frag (kk in [0,12), gn in [0,24)) at
// ((kk*24+gn)*64+lane)*8 bf16 = W[n=gn*16+(lane&15)][k=kk*32+(lane>>4)*8 ..+7]
__global__ void pack_w(const float* __restrict__ W, unsigned short* __restrict__ Wp) {
    int gid  = blockIdx.x * 256 + threadIdx.x;   // 18432
    int lane = gid & 63;
    int u    = gid >> 6;                         // [0,288)
    int gn   = u % 24;
    int kk   = u / 24;
    int c    = lane & 15, quad = lane >> 4;
    const float* src = W + (gn * 16 + c) * K_N + kk * 32 + quad * 8;
    ushort4 lo, hi;
    lo.x = f2bf(src[0]); lo.y = f2bf(src[1]); lo.z = f2bf(src[2]); lo.w = f2bf(src[3]);
    hi.x = f2bf(src[4]); hi.y = f2bf(src[5]); hi.z = f2bf(src[6]); hi.w = f2bf(src[7]);
    ushort4* dst = (ushort4*)(Wp + (size_t)gid * 8);
    dst[0] = lo; dst[1] = hi;
}

// One block per (b, pass); 512 threads = 8 waves; wave owns cols wv*48..+47.
// M in 4 IDENTICAL chunks of 64 rows (rows >= 200 zero-padded, weight 0 via
// -1e30 score). acc[4][3] v4f = 48 regs, all indexing compile-time constant.
// R7 = R5 with ONLY the staging decode swapped to the coalesced form
// (16 consecutive lanes cover one embedding row contiguously).
__global__ __launch_bounds__(512, 4)
void c2v_fused(const int* __restrict__ xs1, const int* __restrict__ ph1,
               const int* __restrict__ xt1,
               const int* __restrict__ xs2, const int* __restrict__ ph2,
               const int* __restrict__ xt2,
               const float* __restrict__ wemb, const float* __restrict__ pemb,
               const unsigned short* __restrict__ Wp,
               const float* __restrict__ attn,
               float* __restrict__ out)
{
    const int tid  = threadIdx.x;
    const int wv   = tid >> 6;
    const int lane = tid & 63;
    const int quad = lane >> 4;
    const int c    = lane & 15;
    const int b    = blockIdx.x;
    const int pass = blockIdx.y;

    const int* xs = pass ? xs2 : xs1;
    const int* ph = pass ? ph2 : ph1;
    const int* xt = pass ? xt2 : xt1;

    __shared__ unsigned short Alds[64 * ASTR];   // 50176 B: one 64-row chunk, all 384 k
    __shared__ float sp[8][64];                  // per-wave score partials
    __shared__ float alds[68];                   // [0..63] e, [64] alpha, [65] Z
    __shared__ int   ilds[3 * 208];

    for (int u = tid; u < 624; u += 512) {
        int s = u / 208, g = u - s * 208;
        const int* tab = (s == 0) ? xs : (s == 1) ? ph : xt;
        ilds[u] = (g < L_N) ? tab[b * L_N + g] : 0;
    }

    const float an0 = attn[(wv * 3 + 0) * 16 + c];
    const float an1 = attn[(wv * 3 + 1) * 16 + c];
    const float an2 = attn[(wv * 3 + 2) * 16 + c];

    float o0 = 0.f, o1 = 0.f, o2 = 0.f;   // running unnormalized col sums
    float Mrun = -1e30f, Zrun = 0.f;      // wave-0 softmax state (uniform in wave)

    const v4u* wp4 = (const v4u*)Wp;

    for (int chunk = 0; chunk < 4; ++chunk) {
        const int row0 = chunk * 64;

        v4f acc[4][3];
        #pragma unroll
        for (int i = 0; i < 4; ++i)
            #pragma unroll
            for (int j = 0; j < 3; ++j)
                acc[i][j] = (v4f){0.f, 0.f, 0.f, 0.f};

        __syncthreads();   // Alds/sp/alds of previous chunk fully consumed

        // stage 64 rows x 3 segs x 128 elems = 3072 8-elem units (6/thread).
        // Coalesced: 16 consecutive lanes cover one row's 512 B contiguously.
        #pragma unroll 2
        for (int i = 0; i < 6; ++i) {
            int u = i * 512 + tid;
            int s = u >> 10;            // seg 0..2 (1024 units per seg)
            int r = u & 1023;
            int m = r >> 4;             // row within chunk, 0..63
            int j = r & 15;             // 8-elem unit within seg, 0..15
            int g = row0 + m;
            ushort4 lo, hi;
            if (g < L_N) {
                const float* ebase = (s == 1) ? pemb : wemb;
                const float* src = ebase + (size_t)ilds[s * 208 + g] * E_N + j * 8;
                const float4 f0 = *(const float4*)(src);
                const float4 f1 = *(const float4*)(src + 4);
                lo.x = f2bf(f0.x); lo.y = f2bf(f0.y); lo.z = f2bf(f0.z); lo.w = f2bf(f0.w);
                hi.x = f2bf(f1.x); hi.y = f2bf(f1.y); hi.z = f2bf(f1.z); hi.w = f2bf(f1.w);
            } else {
                lo.x = lo.y = lo.z = lo.w = 0;
                hi.x = hi.y = hi.z = hi.w = 0;
            }
            ushort4* dst = (ushort4*)&Alds[m * ASTR + s * 128 + j * 8];
            dst[0] = lo; dst[1] = hi;
        }
        __syncthreads();

        // 12 k-steps, no barriers inside (R5-identical: in-loop Wp loads)
        #pragma unroll 2
        for (int kk = 0; kk < 12; ++kk) {
            v8bf b0 = __builtin_bit_cast(v8bf, wp4[(kk * 24 + wv * 3 + 0) * 64 + lane]);
            v8bf b1 = __builtin_bit_cast(v8bf, wp4[(kk * 24 + wv * 3 + 1) * 64 + lane]);
            v8bf b2 = __builtin_bit_cast(v8bf, wp4[(kk * 24 + wv * 3 + 2) * 64 + lane]);
            #pragma unroll
            for (int mt = 0; mt < 4; ++mt) {
                v8bf a = *(const v8bf*)&Alds[(mt * 16 + c) * ASTR + kk * 32 + quad * 8];
                acc[mt][0] = __builtin_amdgcn_mfma_f32_16x16x32_bf16(a, b0, acc[mt][0], 0, 0, 0);
                acc[mt][1] = __builtin_amdgcn_mfma_f32_16x16x32_bf16(a, b1, acc[mt][1], 0, 0, 0);
                acc[mt][2] = __builtin_amdgcn_mfma_f32_16x16x32_bf16(a, b2, acc[mt][2], 0, 0, 0);
            }
        }

        // tanh + per-wave score partials (all-constant indexing)
        #pragma unroll
        for (int mt = 0; mt < 4; ++mt) {
            #pragma unroll
            for (int r = 0; r < 4; ++r) {
                float h0 = fast_tanh(acc[mt][0][r]);
                float h1 = fast_tanh(acc[mt][1][r]);
                float h2 = fast_tanh(acc[mt][2][r]);
                acc[mt][0][r] = h0; acc[mt][1][r] = h1; acc[mt][2][r] = h2;
                float sv = h0 * an0 + h1 * an1 + h2 * an2;
                sv += __shfl_xor(sv, 1);
                sv += __shfl_xor(sv, 2);
                sv += __shfl_xor(sv, 4);
                sv += __shfl_xor(sv, 8);
                if (c == 0) sp[wv][mt * 16 + quad * 4 + r] = sv;
            }
        }
        __syncthreads();

        // wave 0: one lane per row; chunk softmax piece + online merge
        if (wv == 0) {
            int g = row0 + lane;
            float s = sp[0][lane] + sp[1][lane] + sp[2][lane] + sp[3][lane]
                    + sp[4][lane] + sp[5][lane] + sp[6][lane] + sp[7][lane];
            if (g >= L_N) s = -1e30f;
            float mx = s;
            #pragma unroll
            for (int off = 32; off > 0; off >>= 1) mx = fmaxf(mx, __shfl_xor(mx, off));
            float Mnew  = fmaxf(Mrun, mx);
            float alpha = __expf(Mrun - Mnew);
            float e = (g < L_N) ? __expf(s - Mnew) : 0.f;
            float zc = e;
            #pragma unroll
            for (int off = 32; off > 0; off >>= 1) zc += __shfl_xor(zc, off);
            Zrun = Zrun * alpha + zc;
            Mrun = Mnew;
            alds[lane] = e;
            if (lane == 0) alds[64] = alpha;
        }
        __syncthreads();

        // rescale running O, add this chunk's weighted rows
        const float al = alds[64];
        float p0 = 0.f, p1 = 0.f, p2 = 0.f;
        #pragma unroll
        for (int mt = 0; mt < 4; ++mt) {
            #pragma unroll
            for (int r = 0; r < 4; ++r) {
                float w = alds[mt * 16 + quad * 4 + r];
                p0 += w * acc[mt][0][r];
                p1 += w * acc[mt][1][r];
                p2 += w * acc[mt][2][r];
            }
        }
        o0 = o0 * al + p0;
        o1 = o1 * al + p1;
        o2 = o2 * al + p2;
    }

    if (tid == 0) alds[65] = Zrun;
    __syncthreads();
    const float zinv = 1.f / alds[65];

    float* outp = out + (size_t)(pass * B_N + b) * D_N;
    o0 += __shfl_xor(o0, 16); o0 += __shfl_xor(o0, 32);
    o1 += __shfl_xor(o1, 16); o1 += __shfl_xor(o1, 32);
    o2 += __shfl_xor(o2, 16); o2 += __shfl_xor(o2, 32);
    if (quad == 0) {
        outp[(wv * 3 + 0) * 16 + c] = o0 * zinv;
        outp[(wv * 3 + 1) * 16 + c] = o1 * zinv;
        outp[(wv * 3 + 2) * 16 + c] = o2 * zinv;
    }
}

extern "C" void kernel_launch(void* const* d_in, const int* in_sizes, int n_in,
                              void* d_out, int out_size, void* d_ws, size_t ws_size,
                              hipStream_t stream) {
    unsigned short* Wp = (unsigned short*)d_ws;   // 294912 B
    pack_w<<<72, 256, 0, stream>>>((const float*)d_in[8], Wp);
    dim3 grid(B_N, 2, 1);
    c2v_fused<<<grid, 512, 0, stream>>>(
        (const int*)d_in[0], (const int*)d_in[1], (const int*)d_in[2],
        (const int*)d_in[3], (const int*)d_in[4], (const int*)d_in[5],
        (const float*)d_in[6], (const float*)d_in[7],
        Wp, (const float*)d_in[9],
        (float*)d_out);
}